// Round 1
// baseline (902.541 us; speedup 1.0000x reference)
//
#include <hip/hip_runtime.h>
#include <hip/hip_bf16.h>

#define BATCH   16
#define NN      1024
#define ROWS    32      // rows of scores per workgroup
#define NWAVES  4       // 256 threads
#define KSTEP   32      // K per MFMA step (16x16x32)
#define NCT     16      // 16-wide col tiles per wave -> 256 cols/wave

typedef __attribute__((ext_vector_type(8))) short short8;   // 8 x bf16
typedef __attribute__((ext_vector_type(4))) float f32x4;

static __device__ __forceinline__ unsigned short cvt_bf16(float f) {
    // round-to-nearest-even fp32 -> bf16
    unsigned int u = __builtin_bit_cast(unsigned int, f);
    u += 0x7fffu + ((u >> 16) & 1u);
    return (unsigned short)(u >> 16);
}

static __device__ __forceinline__ short8 cvt8(float4 u0, float4 u1) {
    short8 r;
    r[0] = (short)cvt_bf16(u0.x); r[1] = (short)cvt_bf16(u0.y);
    r[2] = (short)cvt_bf16(u0.z); r[3] = (short)cvt_bf16(u0.w);
    r[4] = (short)cvt_bf16(u1.x); r[5] = (short)cvt_bf16(u1.y);
    r[6] = (short)cvt_bf16(u1.z); r[7] = (short)cvt_bf16(u1.w);
    return r;
}

__global__ __launch_bounds__(256, 2)
void attn_fused_kernel(const float* __restrict__ x, float* __restrict__ out) {
    const int b    = blockIdx.y;
    const int i0   = blockIdx.x * ROWS;
    const int tid  = threadIdx.x;
    const int lane = tid & 63;
    const int wid  = tid >> 6;
    const int l15  = lane & 15;   // M/N index within a 16-tile
    const int g    = lane >> 4;   // K-group (and C/D row group)

    const float* xb = x + (size_t)b * NN * NN;

    // A rows as bf16, XOR-swizzled: elem index e = (row*NN + d) ^ ((row&7)<<3)
    __shared__ unsigned short ldsA[ROWS * NN];          // 64 KiB
    __shared__ float redbuf[NWAVES][ROWS];              // cross-wave reduce

    // ---- stage A = x[b, i0:i0+32, :] -> LDS bf16 (coalesced float4 reads) ----
    {
        const float* Ar = xb + (size_t)i0 * NN;
        for (int it = 0; it < (ROWS * NN / 4) / 256; ++it) {  // 32 iters
            int f4  = tid + it * 256;
            int row = f4 >> 8;                // 256 float4 per row
            int d   = (f4 & 255) << 2;
            float4 v = *reinterpret_cast<const float4*>(Ar + row * NN + d);
            int e = (row * NN + d) ^ ((row & 7) << 3);
            ushort4 h;
            h.x = cvt_bf16(v.x); h.y = cvt_bf16(v.y);
            h.z = cvt_bf16(v.z); h.w = cvt_bf16(v.w);
            *reinterpret_cast<ushort4*>(&ldsA[e]) = h;
        }
    }
    __syncthreads();

    // ---- K-loop: scores chunk (32 rows x 256 cols) in registers ----
    f32x4 acc[2][NCT];
    #pragma unroll
    for (int r = 0; r < 2; ++r)
        #pragma unroll
        for (int ct = 0; ct < NCT; ++ct)
            acc[r][ct] = (f32x4){0.f, 0.f, 0.f, 0.f};

    const int jb = wid * (NCT * 16);                    // wave's col base
    const float* Bbase = xb + (size_t)(jb + l15) * NN + g * 8;

    #pragma unroll 1
    for (int k = 0; k < NN; k += KSTEP) {
        // A fragments from swizzled LDS (conflict-free ds_read_b128)
        int e0 = ((l15) * NN + k + g * 8) ^ ((l15 & 7) << 3);
        int e1 = ((16 + l15) * NN + k + g * 8) ^ ((l15 & 7) << 3);
        short8 a0 = *reinterpret_cast<const short8*>(&ldsA[e0]);
        short8 a1 = *reinterpret_cast<const short8*>(&ldsA[e1]);

        #pragma unroll 4
        for (int ct = 0; ct < NCT; ++ct) {
            const float* p = Bbase + ct * (16 * NN) + k;
            float4 u0 = *reinterpret_cast<const float4*>(p);
            float4 u1 = *reinterpret_cast<const float4*>(p + 4);
            short8 bf = cvt8(u0, u1);
            acc[0][ct] = __builtin_amdgcn_mfma_f32_16x16x32_bf16(a0, bf, acc[0][ct], 0, 0, 0);
            acc[1][ct] = __builtin_amdgcn_mfma_f32_16x16x32_bf16(a1, bf, acc[1][ct], 0, 0, 0);
        }
    }

    // ---- softmax over full rows (cols split across 4 waves) ----
    // C/D layout: col = l15, row-in-tile = 4*g + q
    float mrow[2][4];
    #pragma unroll
    for (int r = 0; r < 2; ++r)
        #pragma unroll
        for (int q = 0; q < 4; ++q) {
            float m = acc[r][0][q];
            #pragma unroll
            for (int ct = 1; ct < NCT; ++ct) m = fmaxf(m, acc[r][ct][q]);
            #pragma unroll
            for (int s = 1; s < 16; s <<= 1) m = fmaxf(m, __shfl_xor(m, s, 64));
            mrow[r][q] = m;
        }
    if (l15 == 0) {
        #pragma unroll
        for (int r = 0; r < 2; ++r)
            #pragma unroll
            for (int q = 0; q < 4; ++q)
                redbuf[wid][r * 16 + g * 4 + q] = mrow[r][q];
    }
    __syncthreads();
    #pragma unroll
    for (int r = 0; r < 2; ++r)
        #pragma unroll
        for (int q = 0; q < 4; ++q) {
            int row = r * 16 + g * 4 + q;
            float m = redbuf[0][row];
            m = fmaxf(m, redbuf[1][row]);
            m = fmaxf(m, redbuf[2][row]);
            m = fmaxf(m, redbuf[3][row]);
            mrow[r][q] = m;
        }
    __syncthreads();   // done reading maxes; redbuf will be reused for sums

    float srow[2][4];
    #pragma unroll
    for (int r = 0; r < 2; ++r)
        #pragma unroll
        for (int q = 0; q < 4; ++q) {
            float s = 0.f;
            #pragma unroll
            for (int ct = 0; ct < NCT; ++ct) {
                float e = __expf(acc[r][ct][q] - mrow[r][q]);
                acc[r][ct][q] = e;
                s += e;
            }
            #pragma unroll
            for (int sh = 1; sh < 16; sh <<= 1) s += __shfl_xor(s, sh, 64);
            srow[r][q] = s;
        }
    if (l15 == 0) {
        #pragma unroll
        for (int r = 0; r < 2; ++r)
            #pragma unroll
            for (int q = 0; q < 4; ++q)
                redbuf[wid][r * 16 + g * 4 + q] = srow[r][q];
    }
    __syncthreads();

    float* ob = out + (size_t)b * NN * NN;
    #pragma unroll
    for (int r = 0; r < 2; ++r)
        #pragma unroll
        for (int q = 0; q < 4; ++q) {
            int row = r * 16 + g * 4 + q;
            float tot = redbuf[0][row] + redbuf[1][row] + redbuf[2][row] + redbuf[3][row];
            float inv = 1.0f / tot;
            int i_ = i0 + row;
            const size_t rowoff = (size_t)i_ * NN;
            #pragma unroll
            for (int ct = 0; ct < NCT; ++ct) {
                int j_ = jb + ct * 16 + l15;
                ob[rowoff + j_] = xb[rowoff + j_] * acc[r][ct][q] * inv;
            }
        }
}

extern "C" void kernel_launch(void* const* d_in, const int* in_sizes, int n_in,
                              void* d_out, int out_size, void* d_ws, size_t ws_size,
                              hipStream_t stream) {
    const float* x = (const float*)d_in[0];
    float* out = (float*)d_out;
    dim3 grid(NN / ROWS, BATCH);   // 32 row-blocks x 16 batches = 512 WGs
    attn_fused_kernel<<<grid, 256, 0, stream>>>(x, out);
}

// Round 2
// 190.726 us; speedup vs baseline: 4.7321x; 4.7321x over previous
//
#include <hip/hip_runtime.h>
#include <hip/hip_bf16.h>

#define BATCH   16
#define NN      1024
#define ROWS    64      // score rows per workgroup
#define NWAVES  8
#define NTHR    512
#define KSTEP   32      // K per MFMA step (16x16x32)
#define NCT     8       // 16-wide col tiles per wave -> 128 cols/wave
#define MT      4       // 16-row M tiles per wave   -> 64 rows/wave

typedef __attribute__((ext_vector_type(8))) short short8;   // 8 x bf16
typedef __attribute__((ext_vector_type(4))) float f32x4;

static __device__ __forceinline__ unsigned short cvt_bf16(float f) {
    // round-to-nearest-even fp32 -> bf16
    unsigned int u = __builtin_bit_cast(unsigned int, f);
    u += 0x7fffu + ((u >> 16) & 1u);
    return (unsigned short)(u >> 16);
}

static __device__ __forceinline__ short8 cvt8(float4 u0, float4 u1) {
    short8 r;
    r[0] = (short)cvt_bf16(u0.x); r[1] = (short)cvt_bf16(u0.y);
    r[2] = (short)cvt_bf16(u0.z); r[3] = (short)cvt_bf16(u0.w);
    r[4] = (short)cvt_bf16(u1.x); r[5] = (short)cvt_bf16(u1.y);
    r[6] = (short)cvt_bf16(u1.z); r[7] = (short)cvt_bf16(u1.w);
    return r;
}

// pre-pass: x (fp32) -> bf16 copy in workspace
__global__ __launch_bounds__(256)
void cvt_kernel(const float* __restrict__ x, unsigned short* __restrict__ xw) {
    const int n4 = BATCH * NN * NN / 4;
    int i = blockIdx.x * 256 + threadIdx.x;
    const int stride = gridDim.x * 256;
    for (; i < n4; i += stride) {
        float4 v = reinterpret_cast<const float4*>(x)[i];
        ushort4 h;
        h.x = cvt_bf16(v.x); h.y = cvt_bf16(v.y);
        h.z = cvt_bf16(v.z); h.w = cvt_bf16(v.w);
        reinterpret_cast<ushort4*>(xw)[i] = h;
    }
}

template<int BF16WS>
__global__ __launch_bounds__(NTHR, 2)
void attn_fused(const float* __restrict__ x, const unsigned short* __restrict__ xw,
                float* __restrict__ out) {
    // batch-contiguous XCD swizzle: XCD (wg&7) hosts batches {wg&7, (wg&7)+8}
    const int wg   = blockIdx.x;
    const int t    = wg >> 3;
    const int b    = (wg & 7) + 8 * (t >> 4);
    const int i0   = (t & 15) * ROWS;
    const int tid  = threadIdx.x;
    const int lane = tid & 63;
    const int wid  = tid >> 6;
    const int l15  = lane & 15;   // M/N index within a 16-tile
    const int g    = lane >> 4;   // K-group / C-row group

    const float* xb = x + (size_t)b * NN * NN;

    // A rows bf16, XOR-swizzled: e = (row*NN + d) ^ ((row&15)<<3)
    __shared__ unsigned short ldsA[ROWS * NN];   // 128 KiB
    __shared__ float redbuf[NWAVES][ROWS];       // 2 KiB

    // ---- stage A = x[b, i0:i0+64, :] -> LDS bf16 ----
    if (BF16WS) {
        const unsigned short* Aw = xw + (size_t)b * NN * NN + (size_t)i0 * NN;
        #pragma unroll
        for (int it = 0; it < (ROWS * NN / 4) / NTHR; ++it) {   // 32 iters
            int f4  = tid + it * NTHR;
            int row = f4 >> 8;                  // 256 ushort4 per row
            int d   = (f4 & 255) << 2;
            ushort4 h = *reinterpret_cast<const ushort4*>(Aw + row * NN + d);
            int e = (row * NN + d) ^ ((row & 15) << 3);
            *reinterpret_cast<ushort4*>(&ldsA[e]) = h;
        }
    } else {
        const float* Ar = xb + (size_t)i0 * NN;
        #pragma unroll
        for (int it = 0; it < (ROWS * NN / 4) / NTHR; ++it) {
            int f4  = tid + it * NTHR;
            int row = f4 >> 8;
            int d   = (f4 & 255) << 2;
            float4 v = *reinterpret_cast<const float4*>(Ar + row * NN + d);
            int e = (row * NN + d) ^ ((row & 15) << 3);
            ushort4 h;
            h.x = cvt_bf16(v.x); h.y = cvt_bf16(v.y);
            h.z = cvt_bf16(v.z); h.w = cvt_bf16(v.w);
            *reinterpret_cast<ushort4*>(&ldsA[e]) = h;
        }
    }
    __syncthreads();

    // ---- K-loop: 64x128 score chunk per wave, acc fully static-indexed ----
    f32x4 acc[MT][NCT];
    #pragma unroll
    for (int r = 0; r < MT; ++r)
        #pragma unroll
        for (int ct = 0; ct < NCT; ++ct)
            acc[r][ct] = (f32x4){0.f, 0.f, 0.f, 0.f};

    const int jb = wid * (NCT * 16);            // wave's col base

    if (BF16WS) {
        const unsigned short* Bb = xw + (size_t)b * NN * NN
                                      + (size_t)(jb + l15) * NN + g * 8;
        #pragma unroll 1
        for (int k = 0; k < NN; k += KSTEP) {
            short8 ar[MT];
            #pragma unroll
            for (int r = 0; r < MT; ++r) {
                int e = ((r * 16 + l15) * NN + k + g * 8) ^ (l15 << 3);
                ar[r] = *reinterpret_cast<const short8*>(&ldsA[e]);
            }
            #pragma unroll
            for (int ct = 0; ct < NCT; ++ct) {
                short8 bf = *reinterpret_cast<const short8*>(Bb + ct * (16 * NN) + k);
                #pragma unroll
                for (int r = 0; r < MT; ++r)
                    acc[r][ct] = __builtin_amdgcn_mfma_f32_16x16x32_bf16(
                        ar[r], bf, acc[r][ct], 0, 0, 0);
            }
        }
    } else {
        const float* Bb = xb + (size_t)(jb + l15) * NN + g * 8;
        #pragma unroll 1
        for (int k = 0; k < NN; k += KSTEP) {
            short8 ar[MT];
            #pragma unroll
            for (int r = 0; r < MT; ++r) {
                int e = ((r * 16 + l15) * NN + k + g * 8) ^ (l15 << 3);
                ar[r] = *reinterpret_cast<const short8*>(&ldsA[e]);
            }
            #pragma unroll
            for (int ct = 0; ct < NCT; ++ct) {
                const float* p = Bb + ct * (16 * NN) + k;
                float4 u0 = *reinterpret_cast<const float4*>(p);
                float4 u1 = *reinterpret_cast<const float4*>(p + 4);
                short8 bf = cvt8(u0, u1);
                #pragma unroll
                for (int r = 0; r < MT; ++r)
                    acc[r][ct] = __builtin_amdgcn_mfma_f32_16x16x32_bf16(
                        ar[r], bf, acc[r][ct], 0, 0, 0);
            }
        }
    }

    // ---- softmax over full rows (cols split across 8 waves) ----
    // C/D layout: col = l15, row-in-tile = 4*g + q
    float mrow[MT][4];
    #pragma unroll
    for (int r = 0; r < MT; ++r)
        #pragma unroll
        for (int q = 0; q < 4; ++q) {
            float m = acc[r][0][q];
            #pragma unroll
            for (int ct = 1; ct < NCT; ++ct) m = fmaxf(m, acc[r][ct][q]);
            #pragma unroll
            for (int s = 1; s < 16; s <<= 1) m = fmaxf(m, __shfl_xor(m, s, 64));
            mrow[r][q] = m;
        }
    if (l15 == 0) {
        #pragma unroll
        for (int r = 0; r < MT; ++r)
            #pragma unroll
            for (int q = 0; q < 4; ++q)
                redbuf[wid][r * 16 + g * 4 + q] = mrow[r][q];
    }
    __syncthreads();
    #pragma unroll
    for (int r = 0; r < MT; ++r)
        #pragma unroll
        for (int q = 0; q < 4; ++q) {
            int row = r * 16 + g * 4 + q;
            float m = redbuf[0][row];
            #pragma unroll
            for (int w = 1; w < NWAVES; ++w) m = fmaxf(m, redbuf[w][row]);
            mrow[r][q] = m;
        }
    __syncthreads();   // redbuf reused for sums

    float srow[MT][4];
    #pragma unroll
    for (int r = 0; r < MT; ++r)
        #pragma unroll
        for (int q = 0; q < 4; ++q) {
            float s = 0.f;
            #pragma unroll
            for (int ct = 0; ct < NCT; ++ct) {
                float e = __expf(acc[r][ct][q] - mrow[r][q]);
                acc[r][ct][q] = e;
                s += e;
            }
            #pragma unroll
            for (int sh = 1; sh < 16; sh <<= 1) s += __shfl_xor(s, sh, 64);
            srow[r][q] = s;
        }
    if (l15 == 0) {
        #pragma unroll
        for (int r = 0; r < MT; ++r)
            #pragma unroll
            for (int q = 0; q < 4; ++q)
                redbuf[wid][r * 16 + g * 4 + q] = srow[r][q];
    }
    __syncthreads();

    float* ob = out + (size_t)b * NN * NN;
    #pragma unroll
    for (int r = 0; r < MT; ++r)
        #pragma unroll
        for (int q = 0; q < 4; ++q) {
            int row = r * 16 + g * 4 + q;
            float tot = redbuf[0][row];
            #pragma unroll
            for (int w = 1; w < NWAVES; ++w) tot += redbuf[w][row];
            float inv = 1.0f / tot;
            const size_t rowoff = (size_t)(i0 + row) * NN;
            #pragma unroll
            for (int ct = 0; ct < NCT; ++ct) {
                int j_ = jb + ct * 16 + l15;
                ob[rowoff + j_] = xb[rowoff + j_] * acc[r][ct][q] * inv;
            }
        }
}

extern "C" void kernel_launch(void* const* d_in, const int* in_sizes, int n_in,
                              void* d_out, int out_size, void* d_ws, size_t ws_size,
                              hipStream_t stream) {
    const float* x = (const float*)d_in[0];
    float* out = (float*)d_out;
    const size_t need = (size_t)BATCH * NN * NN * sizeof(unsigned short);  // 32 MiB
    dim3 grid(BATCH * (NN / ROWS));   // 256 WGs, 1 per CU
    if (ws_size >= need) {
        unsigned short* xw = (unsigned short*)d_ws;
        cvt_kernel<<<2048, 256, 0, stream>>>(x, xw);
        attn_fused<1><<<grid, NTHR, 0, stream>>>(x, xw, out);
    } else {
        attn_fused<0><<<grid, NTHR, 0, stream>>>(x, nullptr, out);
    }
}